// Round 1
// baseline (905.235 us; speedup 1.0000x reference)
//
#include <hip/hip_runtime.h>
#include <hip/hip_bf16.h>
#include <cstdint>
#include <cstddef>

typedef __hip_bfloat16 bf16_t;
typedef __attribute__((ext_vector_type(8))) __bf16 bf16x8;
typedef __attribute__((ext_vector_type(4))) float f32x4;

__device__ __forceinline__ void gld_lds16(const void* g, void* l) {
    __builtin_amdgcn_global_load_lds(
        (const __attribute__((address_space(1))) void*)(g),
        (__attribute__((address_space(3))) void*)(l), 16, 0, 0);
}

// ---------------- cast fp32 -> bf16 (n % 4 == 0) ----------------
__global__ void k_cast(const float* __restrict__ in, bf16_t* __restrict__ out, long n) {
    long i = ((long)blockIdx.x * blockDim.x + threadIdx.x) * 4;
    if (i >= n) return;
    float4 v = *(const float4*)(in + i);
    out[i + 0] = __float2bfloat16(v.x);
    out[i + 1] = __float2bfloat16(v.y);
    out[i + 2] = __float2bfloat16(v.z);
    out[i + 3] = __float2bfloat16(v.w);
}

// cast with zero row padding: rows [rows_in, rows_out) -> 0
__global__ void k_cast_pad(const float* __restrict__ in, bf16_t* __restrict__ out,
                           int rows_in, int rows_out, int cols) {
    long i = ((long)blockIdx.x * blockDim.x + threadIdx.x) * 4;
    long n = (long)rows_out * cols;
    if (i >= n) return;
    int r = (int)(i / cols);
    if (r < rows_in) {
        float4 v = *(const float4*)(in + i);
        out[i + 0] = __float2bfloat16(v.x);
        out[i + 1] = __float2bfloat16(v.y);
        out[i + 2] = __float2bfloat16(v.z);
        out[i + 3] = __float2bfloat16(v.w);
    } else {
        bf16_t z = __float2bfloat16(0.f);
        out[i + 0] = z; out[i + 1] = z; out[i + 2] = z; out[i + 3] = z;
    }
}

// ---------------- transpose + cast: in [R,C] fp32 -> out [C,R] bf16 ----------------
// R, C multiples of 32. block 256 = 32x8, grid (C/32, R/32)
__global__ void k_transpose_cast(const float* __restrict__ in, bf16_t* __restrict__ out,
                                 int R, int C) {
    __shared__ float tile[32][33];
    int bx = blockIdx.x * 32;  // col base in `in`
    int by = blockIdx.y * 32;  // row base in `in`
    int tx = threadIdx.x & 31, ty = threadIdx.x >> 5;
    #pragma unroll
    for (int j = 0; j < 32; j += 8)
        tile[ty + j][tx] = in[(size_t)(by + ty + j) * C + bx + tx];
    __syncthreads();
    #pragma unroll
    for (int j = 0; j < 32; j += 8)
        out[(size_t)(bx + ty + j) * R + by + tx] = __float2bfloat16(tile[tx][ty + j]);
}

// ---------------- adapter: v_ip[b][n] = sum_k ae[b][k] * Wva[k][n] ----------------
__global__ void k_adapter(const float* __restrict__ ae, const float* __restrict__ Wva,
                          float* __restrict__ vip) {
    int g = blockIdx.x * 256 + threadIdx.x;  // 0 .. 8*1280-1
    int b = g / 1280, n = g % 1280;
    const float* a = ae + b * 768;
    float acc = 0.f;
    for (int k = 0; k < 768; ++k) acc += a[k] * Wva[(size_t)k * 1280 + n];
    vip[g] = acc;
}

// ---------------- bf16 GEMM: C[M,N] = A[M,K] @ Bt[N,K]^T (+bias) ----------------
// 128x128 tile, BK=32, 4 waves each 64x64 (4x4 of 16x16x32 MFMA). m97 structure.
template <bool OUT_BF16, bool ADD_BIAS>
__global__ __launch_bounds__(256, 2) void k_gemm_bt(
    const bf16_t* __restrict__ A, const bf16_t* __restrict__ Bt,
    void* __restrict__ Cv, const float* __restrict__ bias, int M, int N, int K) {
    __shared__ __align__(16) bf16_t As[128 * 32];
    __shared__ __align__(16) bf16_t Bs[128 * 32];
    const int tid = threadIdx.x;
    const int m0 = blockIdx.y * 128, n0 = blockIdx.x * 128;
    const int wave = tid >> 6, lane = tid & 63;
    const int wm = (wave >> 1) * 64, wn = (wave & 1) * 64;
    const int quad = lane >> 4, l16 = lane & 15;

    f32x4 acc[4][4] = {};

    const int c0 = tid, c1 = tid + 256;
    const int r0 = c0 >> 2, o0 = (c0 & 3) * 8;
    const int r1 = c1 >> 2, o1 = (c1 & 3) * 8;
    const bf16_t* a0 = A + (size_t)(m0 + r0) * K + o0;
    const bf16_t* a1 = A + (size_t)(m0 + r1) * K + o1;
    const bf16_t* b0 = Bt + (size_t)(n0 + r0) * K + o0;
    const bf16_t* b1 = Bt + (size_t)(n0 + r1) * K + o1;

    for (int k0 = 0; k0 < K; k0 += 32) {
        __syncthreads();
        gld_lds16(a0 + k0, As + c0 * 8);
        gld_lds16(a1 + k0, As + c1 * 8);
        gld_lds16(b0 + k0, Bs + c0 * 8);
        gld_lds16(b1 + k0, Bs + c1 * 8);
        __syncthreads();
        bf16x8 af[4], bfv[4];
        #pragma unroll
        for (int t = 0; t < 4; ++t) {
            af[t]  = *(const bf16x8*)(As + (wm + t * 16 + l16) * 32 + quad * 8);
            bfv[t] = *(const bf16x8*)(Bs + (wn + t * 16 + l16) * 32 + quad * 8);
        }
        #pragma unroll
        for (int mt = 0; mt < 4; ++mt)
            #pragma unroll
            for (int nt = 0; nt < 4; ++nt)
                acc[mt][nt] = __builtin_amdgcn_mfma_f32_16x16x32_bf16(af[mt], bfv[nt], acc[mt][nt], 0, 0, 0);
    }

    if constexpr (OUT_BF16) {
        bf16_t* C = (bf16_t*)Cv;
        #pragma unroll
        for (int mt = 0; mt < 4; ++mt)
            #pragma unroll
            for (int rg = 0; rg < 4; ++rg) {
                int row = m0 + wm + mt * 16 + quad * 4 + rg;
                #pragma unroll
                for (int nt = 0; nt < 4; ++nt) {
                    int col = n0 + wn + nt * 16 + l16;
                    C[(size_t)row * N + col] = __float2bfloat16(acc[mt][nt][rg]);
                }
            }
    } else {
        float* C = (float*)Cv;
        float bv[4];
        #pragma unroll
        for (int nt = 0; nt < 4; ++nt)
            bv[nt] = ADD_BIAS ? bias[n0 + wn + nt * 16 + l16] : 0.f;
        #pragma unroll
        for (int mt = 0; mt < 4; ++mt)
            #pragma unroll
            for (int rg = 0; rg < 4; ++rg) {
                int row = m0 + wm + mt * 16 + quad * 4 + rg;
                #pragma unroll
                for (int nt = 0; nt < 4; ++nt) {
                    int col = n0 + wn + nt * 16 + l16;
                    C[(size_t)row * N + col] = acc[mt][nt][rg] + bv[nt];
                }
            }
    }
}

// ---------------- fused attention for one (b, h, 128-query tile) ----------------
// Sk = 77 keys, padded to 96 (zeros) for MFMA. Epilogue adds v_ip broadcast.
__global__ __launch_bounds__(256, 2) void k_attn(
    const bf16_t* __restrict__ Q, const bf16_t* __restrict__ Kc,
    const bf16_t* __restrict__ Vc, const float* __restrict__ vip,
    bf16_t* __restrict__ Mrg) {
    __shared__ __align__(16) bf16_t Qs[128 * 64];
    __shared__ __align__(16) bf16_t Ks[96 * 64];   // Ks[kk][d], rows 77..95 zero
    __shared__ __align__(16) bf16_t Vt[64 * 96];   // Vt[d][kk], kk 77..95 zero
    __shared__ __align__(16) bf16_t Ps[128 * 96];  // scores, then probs
    const int tid = threadIdx.x;
    const int qb = blockIdx.x, h = blockIdx.y, b = blockIdx.z;
    const int wave = tid >> 6, lane = tid & 63;
    const int quad = lane >> 4, l16 = lane & 15;

    // Q tile -> LDS via global_load_lds (16B chunks, lane-contiguous LDS layout)
    const bf16_t* Qg = Q + ((size_t)(b * 4096 + qb * 128)) * 1280 + h * 64;
    #pragma unroll
    for (int j = 0; j < 4; ++j) {
        int c = tid + j * 256;
        int r = c >> 3, o = (c & 7) * 8;
        gld_lds16(Qg + (size_t)r * 1280 + o, Qs + c * 8);
    }
    // zero pads (disjoint from valid-data writes; one barrier before use)
    bf16_t z = __float2bfloat16(0.f);
    for (int i = 77 * 64 + tid; i < 96 * 64; i += 256) Ks[i] = z;
    for (int i = tid; i < 64 * 19; i += 256) {
        int d = i / 19, kk = 77 + i % 19;
        Vt[d * 96 + kk] = z;
    }
    // K, V valid rows (77 rows x 64 d = 616 16B-chunks)
    for (int c = tid; c < 616; c += 256) {
        int r = c >> 3, o = (c & 7) * 8;
        size_t gi = ((size_t)(b * 77 + r)) * 1280 + h * 64 + o;
        int4 kv = *(const int4*)(Kc + gi);
        *(int4*)(Ks + r * 64 + o) = kv;
        int4 vv = *(const int4*)(Vc + gi);
        const bf16_t* ve = (const bf16_t*)&vv;
        #pragma unroll
        for (int j = 0; j < 8; ++j) Vt[(o + j) * 96 + r] = ve[j];
    }
    __syncthreads();

    // scores = Q @ K^T : each wave 32 rows x 96 cols, Kdim=64 (2 steps)
    f32x4 sacc[2][6] = {};
    #pragma unroll
    for (int ks = 0; ks < 2; ++ks) {
        bf16x8 aq[2], bk[6];
        #pragma unroll
        for (int mt = 0; mt < 2; ++mt)
            aq[mt] = *(const bf16x8*)(Qs + (wave * 32 + mt * 16 + l16) * 64 + ks * 32 + quad * 8);
        #pragma unroll
        for (int nt = 0; nt < 6; ++nt)
            bk[nt] = *(const bf16x8*)(Ks + (nt * 16 + l16) * 64 + ks * 32 + quad * 8);
        #pragma unroll
        for (int mt = 0; mt < 2; ++mt)
            #pragma unroll
            for (int nt = 0; nt < 6; ++nt)
                sacc[mt][nt] = __builtin_amdgcn_mfma_f32_16x16x32_bf16(aq[mt], bk[nt], sacc[mt][nt], 0, 0, 0);
    }
    // write scaled scores (padded cols are exactly 0 -> probs 0 after softmax pass)
    #pragma unroll
    for (int mt = 0; mt < 2; ++mt)
        #pragma unroll
        for (int nt = 0; nt < 6; ++nt)
            #pragma unroll
            for (int rg = 0; rg < 4; ++rg) {
                int row = wave * 32 + mt * 16 + quad * 4 + rg;
                int col = nt * 16 + l16;
                Ps[row * 96 + col] = __float2bfloat16(sacc[mt][nt][rg] * 0.125f);
            }
    __syncthreads();

    // softmax over 77 valid cols: 2 threads per row, combine via shfl_xor(1)
    {
        int row = tid >> 1, half = tid & 1;
        int cbeg = half ? 39 : 0, cend = half ? 77 : 39;
        bf16_t* prow = Ps + row * 96;
        float mx = -1e30f;
        for (int c = cbeg; c < cend; ++c) mx = fmaxf(mx, __bfloat162float(prow[c]));
        mx = fmaxf(mx, __shfl_xor(mx, 1));
        float sm = 0.f;
        for (int c = cbeg; c < cend; ++c) sm += __expf(__bfloat162float(prow[c]) - mx);
        sm += __shfl_xor(sm, 1);
        float inv = 1.f / sm;
        for (int c = cbeg; c < cend; ++c)
            prow[c] = __float2bfloat16(__expf(__bfloat162float(prow[c]) - mx) * inv);
    }
    __syncthreads();

    // O = P @ V : each wave 32 rows x 64 cols, Kdim=96 (3 steps)
    f32x4 oacc[2][4] = {};
    #pragma unroll
    for (int ks = 0; ks < 3; ++ks) {
        bf16x8 ap[2], bv[4];
        #pragma unroll
        for (int mt = 0; mt < 2; ++mt)
            ap[mt] = *(const bf16x8*)(Ps + (wave * 32 + mt * 16 + l16) * 96 + ks * 32 + quad * 8);
        #pragma unroll
        for (int nt = 0; nt < 4; ++nt)
            bv[nt] = *(const bf16x8*)(Vt + (nt * 16 + l16) * 96 + ks * 32 + quad * 8);
        #pragma unroll
        for (int mt = 0; mt < 2; ++mt)
            #pragma unroll
            for (int nt = 0; nt < 4; ++nt)
                oacc[mt][nt] = __builtin_amdgcn_mfma_f32_16x16x32_bf16(ap[mt], bv[nt], oacc[mt][nt], 0, 0, 0);
    }
    // epilogue: + v_ip broadcast (IP-adapter single-key branch), store bf16 merged
    #pragma unroll
    for (int nt = 0; nt < 4; ++nt) {
        int col = nt * 16 + l16;
        float add = vip[b * 1280 + h * 64 + col];
        #pragma unroll
        for (int mt = 0; mt < 2; ++mt)
            #pragma unroll
            for (int rg = 0; rg < 4; ++rg) {
                int row = wave * 32 + mt * 16 + quad * 4 + rg;
                Mrg[((size_t)(b * 4096 + qb * 128 + row)) * 1280 + h * 64 + col] =
                    __float2bfloat16(oacc[mt][nt][rg] + add);
            }
    }
}

extern "C" void kernel_launch(void* const* d_in, const int* in_sizes, int n_in,
                              void* d_out, int out_size, void* d_ws, size_t ws_size,
                              hipStream_t stream) {
    (void)in_sizes; (void)n_in; (void)out_size; (void)ws_size;
    const float* hs  = (const float*)d_in[0];  // [8,4096,1280]
    const float* enc = (const float*)d_in[1];  // [8,77,2048]
    const float* ae  = (const float*)d_in[2];  // [8,1,768]
    const float* Wq  = (const float*)d_in[3];  // [1280,1280]
    const float* Wk  = (const float*)d_in[4];  // [2048,1280]
    const float* Wv  = (const float*)d_in[5];  // [2048,1280]
    // d_in[6] = Wk_adapter: unused — softmax over a single key is identically 1
    const float* Wva = (const float*)d_in[7];  // [768,1280]
    const float* Wo  = (const float*)d_in[8];  // [1280,1280]
    const float* bo  = (const float*)d_in[9];  // [1280]
    float* out = (float*)d_out;

    char* ws = (char*)d_ws;
    size_t off = 0;
    auto alloc = [&](size_t bytes) -> void* {
        void* p = ws + off;
        off += (bytes + 255) & ~(size_t)255;
        return p;
    };
    bf16_t* Xb  = (bf16_t*)alloc((size_t)32768 * 1280 * 2);  // bf16 X
    bf16_t* Qb  = (bf16_t*)alloc((size_t)32768 * 1280 * 2);  // bf16 Q
    bf16_t* Mrg = (bf16_t*)alloc((size_t)32768 * 1280 * 2);  // bf16 merged
    bf16_t* Eb  = (bf16_t*)alloc((size_t)640 * 2048 * 2);    // bf16 E, padded to 640 rows
    bf16_t* WqT = (bf16_t*)alloc((size_t)1280 * 1280 * 2);
    bf16_t* WkT = (bf16_t*)alloc((size_t)1280 * 2048 * 2);
    bf16_t* WvT = (bf16_t*)alloc((size_t)1280 * 2048 * 2);
    bf16_t* WoT = (bf16_t*)alloc((size_t)1280 * 1280 * 2);
    bf16_t* Kc  = (bf16_t*)alloc((size_t)640 * 1280 * 2);    // padded rows
    bf16_t* Vc  = (bf16_t*)alloc((size_t)640 * 1280 * 2);
    float*  vip = (float*)alloc((size_t)8 * 1280 * 4);

    // pre-pass: casts / transposes / adapter value
    k_cast<<<40960, 256, 0, stream>>>(hs, Xb, (long)32768 * 1280);
    k_cast_pad<<<1280, 256, 0, stream>>>(enc, Eb, 616, 640, 2048);
    k_transpose_cast<<<dim3(40, 40), 256, 0, stream>>>(Wq, WqT, 1280, 1280);
    k_transpose_cast<<<dim3(40, 64), 256, 0, stream>>>(Wk, WkT, 2048, 1280);
    k_transpose_cast<<<dim3(40, 64), 256, 0, stream>>>(Wv, WvT, 2048, 1280);
    k_transpose_cast<<<dim3(40, 40), 256, 0, stream>>>(Wo, WoT, 1280, 1280);
    k_adapter<<<40, 256, 0, stream>>>(ae, Wva, vip);

    // projections
    k_gemm_bt<true, false><<<dim3(10, 256), 256, 0, stream>>>(Xb, WqT, Qb, nullptr, 32768, 1280, 1280);
    k_gemm_bt<true, false><<<dim3(10, 5), 256, 0, stream>>>(Eb, WkT, Kc, nullptr, 640, 1280, 2048);
    k_gemm_bt<true, false><<<dim3(10, 5), 256, 0, stream>>>(Eb, WvT, Vc, nullptr, 640, 1280, 2048);

    // fused attention + IP-adapter broadcast add
    k_attn<<<dim3(32, 20, 8), 256, 0, stream>>>(Qb, Kc, Vc, vip, Mrg);

    // output projection + bias -> fp32 d_out
    k_gemm_bt<false, true><<<dim3(10, 256), 256, 0, stream>>>(Mrg, WoT, out, bo, 32768, 1280, 1280);
}

// Round 2
// 867.660 us; speedup vs baseline: 1.0433x; 1.0433x over previous
//
#include <hip/hip_runtime.h>
#include <hip/hip_bf16.h>
#include <cstdint>
#include <cstddef>

typedef __hip_bfloat16 bf16_t;
typedef __attribute__((ext_vector_type(8))) __bf16 bf16x8;
typedef __attribute__((ext_vector_type(4))) float f32x4;

__device__ __forceinline__ void gld_lds16(const void* g, void* l) {
    __builtin_amdgcn_global_load_lds(
        (const __attribute__((address_space(1))) void*)(g),
        (__attribute__((address_space(3))) void*)(l), 16, 0, 0);
}

// ---------------- cast fp32 -> bf16 (n % 4 == 0) ----------------
__global__ void k_cast(const float* __restrict__ in, bf16_t* __restrict__ out, long n) {
    long i = ((long)blockIdx.x * blockDim.x + threadIdx.x) * 4;
    if (i >= n) return;
    float4 v = *(const float4*)(in + i);
    out[i + 0] = __float2bfloat16(v.x);
    out[i + 1] = __float2bfloat16(v.y);
    out[i + 2] = __float2bfloat16(v.z);
    out[i + 3] = __float2bfloat16(v.w);
}

// cast with zero row padding: rows [rows_in, rows_out) -> 0
__global__ void k_cast_pad(const float* __restrict__ in, bf16_t* __restrict__ out,
                           int rows_in, int rows_out, int cols) {
    long i = ((long)blockIdx.x * blockDim.x + threadIdx.x) * 4;
    long n = (long)rows_out * cols;
    if (i >= n) return;
    int r = (int)(i / cols);
    if (r < rows_in) {
        float4 v = *(const float4*)(in + i);
        out[i + 0] = __float2bfloat16(v.x);
        out[i + 1] = __float2bfloat16(v.y);
        out[i + 2] = __float2bfloat16(v.z);
        out[i + 3] = __float2bfloat16(v.w);
    } else {
        bf16_t z = __float2bfloat16(0.f);
        out[i + 0] = z; out[i + 1] = z; out[i + 2] = z; out[i + 3] = z;
    }
}

// ---------------- transpose + cast: in [R,C] fp32 -> out [C,R] bf16 ----------------
__global__ void k_transpose_cast(const float* __restrict__ in, bf16_t* __restrict__ out,
                                 int R, int C) {
    __shared__ float tile[32][33];
    int bx = blockIdx.x * 32;
    int by = blockIdx.y * 32;
    int tx = threadIdx.x & 31, ty = threadIdx.x >> 5;
    #pragma unroll
    for (int j = 0; j < 32; j += 8)
        tile[ty + j][tx] = in[(size_t)(by + ty + j) * C + bx + tx];
    __syncthreads();
    #pragma unroll
    for (int j = 0; j < 32; j += 8)
        out[(size_t)(bx + ty + j) * R + by + tx] = __float2bfloat16(tile[tx][ty + j]);
}

// ---------------- adapter: v_ip[b][n] = sum_k ae[b][k] * Wva[k][n] ----------------
__global__ void k_adapter(const float* __restrict__ ae, const float* __restrict__ Wva,
                          float* __restrict__ vip) {
    int g = blockIdx.x * 256 + threadIdx.x;
    int b = g / 1280, n = g % 1280;
    const float* a = ae + b * 768;
    float acc = 0.f;
    for (int k = 0; k < 768; ++k) acc += a[k] * Wva[(size_t)k * 1280 + n];
    vip[g] = acc;
}

// ---------------- bf16 GEMM: C[M,N] = A[M,K] @ Bt[N,K]^T (+bias) ----------------
// 128x128 tile, BK=32, 4 waves each 64x64. m97 structure.
// SWZ: 1-D grid, XCD-aware swizzle — xcd = id&7 gets a contiguous band of
// mtx M-tiles, iterating snt N-tiles innermost, so A row-tiles get L2 reuse
// within one XCD instead of being pulled into 8 different per-XCD L2s.
template <bool OUT_BF16, bool ADD_BIAS, bool SWZ>
__global__ __launch_bounds__(256, 2) void k_gemm_bt(
    const bf16_t* __restrict__ A, const bf16_t* __restrict__ Bt,
    void* __restrict__ Cv, const float* __restrict__ bias, int M, int N, int K,
    int snt, int mtx) {
    __shared__ __align__(16) bf16_t As[128 * 32];
    __shared__ __align__(16) bf16_t Bs[128 * 32];
    const int tid = threadIdx.x;
    int m0, n0;
    if constexpr (SWZ) {
        int id = blockIdx.x;
        int xcd = id & 7, j = id >> 3;
        m0 = (xcd * mtx + j / snt) * 128;
        n0 = (j % snt) * 128;
    } else {
        m0 = blockIdx.y * 128;
        n0 = blockIdx.x * 128;
    }
    const int wave = tid >> 6, lane = tid & 63;
    const int wm = (wave >> 1) * 64, wn = (wave & 1) * 64;
    const int quad = lane >> 4, l16 = lane & 15;

    f32x4 acc[4][4] = {};

    const int c0 = tid, c1 = tid + 256;
    const int r0 = c0 >> 2, o0 = (c0 & 3) * 8;
    const int r1 = c1 >> 2, o1 = (c1 & 3) * 8;
    const bf16_t* a0 = A + (size_t)(m0 + r0) * K + o0;
    const bf16_t* a1 = A + (size_t)(m0 + r1) * K + o1;
    const bf16_t* b0 = Bt + (size_t)(n0 + r0) * K + o0;
    const bf16_t* b1 = Bt + (size_t)(n0 + r1) * K + o1;

    for (int k0 = 0; k0 < K; k0 += 32) {
        __syncthreads();
        gld_lds16(a0 + k0, As + c0 * 8);
        gld_lds16(a1 + k0, As + c1 * 8);
        gld_lds16(b0 + k0, Bs + c0 * 8);
        gld_lds16(b1 + k0, Bs + c1 * 8);
        __syncthreads();
        bf16x8 af[4], bfv[4];
        #pragma unroll
        for (int t = 0; t < 4; ++t) {
            af[t]  = *(const bf16x8*)(As + (wm + t * 16 + l16) * 32 + quad * 8);
            bfv[t] = *(const bf16x8*)(Bs + (wn + t * 16 + l16) * 32 + quad * 8);
        }
        #pragma unroll
        for (int mt = 0; mt < 4; ++mt)
            #pragma unroll
            for (int nt = 0; nt < 4; ++nt)
                acc[mt][nt] = __builtin_amdgcn_mfma_f32_16x16x32_bf16(af[mt], bfv[nt], acc[mt][nt], 0, 0, 0);
    }

    if constexpr (OUT_BF16) {
        bf16_t* C = (bf16_t*)Cv;
        #pragma unroll
        for (int mt = 0; mt < 4; ++mt)
            #pragma unroll
            for (int rg = 0; rg < 4; ++rg) {
                int row = m0 + wm + mt * 16 + quad * 4 + rg;
                #pragma unroll
                for (int nt = 0; nt < 4; ++nt) {
                    int col = n0 + wn + nt * 16 + l16;
                    C[(size_t)row * N + col] = __float2bfloat16(acc[mt][nt][rg]);
                }
            }
    } else {
        float* C = (float*)Cv;
        float bv[4];
        #pragma unroll
        for (int nt = 0; nt < 4; ++nt)
            bv[nt] = ADD_BIAS ? bias[n0 + wn + nt * 16 + l16] : 0.f;
        #pragma unroll
        for (int mt = 0; mt < 4; ++mt)
            #pragma unroll
            for (int rg = 0; rg < 4; ++rg) {
                int row = m0 + wm + mt * 16 + quad * 4 + rg;
                #pragma unroll
                for (int nt = 0; nt < 4; ++nt) {
                    int col = n0 + wn + nt * 16 + l16;
                    C[(size_t)row * N + col] = acc[mt][nt][rg] + bv[nt];
                }
            }
    }
}

// ---------------- fused attention for one (b, h, 128-query tile) ----------------
__global__ __launch_bounds__(256, 2) void k_attn(
    const bf16_t* __restrict__ Q, const bf16_t* __restrict__ Kc,
    const bf16_t* __restrict__ Vc, const float* __restrict__ vip,
    bf16_t* __restrict__ Mrg) {
    __shared__ __align__(16) bf16_t Qs[128 * 64];
    __shared__ __align__(16) bf16_t Ks[96 * 64];
    __shared__ __align__(16) bf16_t Vt[64 * 96];
    __shared__ __align__(16) bf16_t Ps[128 * 96];
    const int tid = threadIdx.x;
    const int qb = blockIdx.x, h = blockIdx.y, b = blockIdx.z;
    const int wave = tid >> 6, lane = tid & 63;
    const int quad = lane >> 4, l16 = lane & 15;

    const bf16_t* Qg = Q + ((size_t)(b * 4096 + qb * 128)) * 1280 + h * 64;
    #pragma unroll
    for (int j = 0; j < 4; ++j) {
        int c = tid + j * 256;
        int r = c >> 3, o = (c & 7) * 8;
        gld_lds16(Qg + (size_t)r * 1280 + o, Qs + c * 8);
    }
    bf16_t z = __float2bfloat16(0.f);
    for (int i = 77 * 64 + tid; i < 96 * 64; i += 256) Ks[i] = z;
    for (int i = tid; i < 64 * 19; i += 256) {
        int d = i / 19, kk = 77 + i % 19;
        Vt[d * 96 + kk] = z;
    }
    for (int c = tid; c < 616; c += 256) {
        int r = c >> 3, o = (c & 7) * 8;
        size_t gi = ((size_t)(b * 77 + r)) * 1280 + h * 64 + o;
        int4 kv = *(const int4*)(Kc + gi);
        *(int4*)(Ks + r * 64 + o) = kv;
        int4 vv = *(const int4*)(Vc + gi);
        const bf16_t* ve = (const bf16_t*)&vv;
        #pragma unroll
        for (int j = 0; j < 8; ++j) Vt[(o + j) * 96 + r] = ve[j];
    }
    __syncthreads();

    f32x4 sacc[2][6] = {};
    #pragma unroll
    for (int ks = 0; ks < 2; ++ks) {
        bf16x8 aq[2], bk[6];
        #pragma unroll
        for (int mt = 0; mt < 2; ++mt)
            aq[mt] = *(const bf16x8*)(Qs + (wave * 32 + mt * 16 + l16) * 64 + ks * 32 + quad * 8);
        #pragma unroll
        for (int nt = 0; nt < 6; ++nt)
            bk[nt] = *(const bf16x8*)(Ks + (nt * 16 + l16) * 64 + ks * 32 + quad * 8);
        #pragma unroll
        for (int mt = 0; mt < 2; ++mt)
            #pragma unroll
            for (int nt = 0; nt < 6; ++nt)
                sacc[mt][nt] = __builtin_amdgcn_mfma_f32_16x16x32_bf16(aq[mt], bk[nt], sacc[mt][nt], 0, 0, 0);
    }
    #pragma unroll
    for (int mt = 0; mt < 2; ++mt)
        #pragma unroll
        for (int nt = 0; nt < 6; ++nt)
            #pragma unroll
            for (int rg = 0; rg < 4; ++rg) {
                int row = wave * 32 + mt * 16 + quad * 4 + rg;
                int col = nt * 16 + l16;
                Ps[row * 96 + col] = __float2bfloat16(sacc[mt][nt][rg] * 0.125f);
            }
    __syncthreads();

    {
        int row = tid >> 1, half = tid & 1;
        int cbeg = half ? 39 : 0, cend = half ? 77 : 39;
        bf16_t* prow = Ps + row * 96;
        float mx = -1e30f;
        for (int c = cbeg; c < cend; ++c) mx = fmaxf(mx, __bfloat162float(prow[c]));
        mx = fmaxf(mx, __shfl_xor(mx, 1));
        float sm = 0.f;
        for (int c = cbeg; c < cend; ++c) sm += __expf(__bfloat162float(prow[c]) - mx);
        sm += __shfl_xor(sm, 1);
        float inv = 1.f / sm;
        for (int c = cbeg; c < cend; ++c)
            prow[c] = __float2bfloat16(__expf(__bfloat162float(prow[c]) - mx) * inv);
    }
    __syncthreads();

    f32x4 oacc[2][4] = {};
    #pragma unroll
    for (int ks = 0; ks < 3; ++ks) {
        bf16x8 ap[2], bv[4];
        #pragma unroll
        for (int mt = 0; mt < 2; ++mt)
            ap[mt] = *(const bf16x8*)(Ps + (wave * 32 + mt * 16 + l16) * 96 + ks * 32 + quad * 8);
        #pragma unroll
        for (int nt = 0; nt < 4; ++nt)
            bv[nt] = *(const bf16x8*)(Vt + (nt * 16 + l16) * 96 + ks * 32 + quad * 8);
        #pragma unroll
        for (int mt = 0; mt < 2; ++mt)
            #pragma unroll
            for (int nt = 0; nt < 4; ++nt)
                oacc[mt][nt] = __builtin_amdgcn_mfma_f32_16x16x32_bf16(ap[mt], bv[nt], oacc[mt][nt], 0, 0, 0);
    }
    #pragma unroll
    for (int nt = 0; nt < 4; ++nt) {
        int col = nt * 16 + l16;
        float add = vip[b * 1280 + h * 64 + col];
        #pragma unroll
        for (int mt = 0; mt < 2; ++mt)
            #pragma unroll
            for (int rg = 0; rg < 4; ++rg) {
                int row = wave * 32 + mt * 16 + quad * 4 + rg;
                Mrg[((size_t)(b * 4096 + qb * 128 + row)) * 1280 + h * 64 + col] =
                    __float2bfloat16(oacc[mt][nt][rg] + add);
            }
    }
}

extern "C" void kernel_launch(void* const* d_in, const int* in_sizes, int n_in,
                              void* d_out, int out_size, void* d_ws, size_t ws_size,
                              hipStream_t stream) {
    (void)in_sizes; (void)n_in; (void)out_size; (void)ws_size;
    const float* hs  = (const float*)d_in[0];
    const float* enc = (const float*)d_in[1];
    const float* ae  = (const float*)d_in[2];
    const float* Wq  = (const float*)d_in[3];
    const float* Wk  = (const float*)d_in[4];
    const float* Wv  = (const float*)d_in[5];
    const float* Wva = (const float*)d_in[7];
    const float* Wo  = (const float*)d_in[8];
    const float* bo  = (const float*)d_in[9];
    float* out = (float*)d_out;

    char* ws = (char*)d_ws;
    size_t off = 0;
    auto alloc = [&](size_t bytes) -> void* {
        void* p = ws + off;
        off += (bytes + 255) & ~(size_t)255;
        return p;
    };
    bf16_t* Xb  = (bf16_t*)alloc((size_t)32768 * 1280 * 2);
    bf16_t* Qb  = (bf16_t*)alloc((size_t)32768 * 1280 * 2);
    bf16_t* Mrg = (bf16_t*)alloc((size_t)32768 * 1280 * 2);
    bf16_t* Eb  = (bf16_t*)alloc((size_t)640 * 2048 * 2);
    bf16_t* WqT = (bf16_t*)alloc((size_t)1280 * 1280 * 2);
    bf16_t* WkT = (bf16_t*)alloc((size_t)1280 * 2048 * 2);
    bf16_t* WvT = (bf16_t*)alloc((size_t)1280 * 2048 * 2);
    bf16_t* WoT = (bf16_t*)alloc((size_t)1280 * 1280 * 2);
    bf16_t* Kc  = (bf16_t*)alloc((size_t)640 * 1280 * 2);
    bf16_t* Vc  = (bf16_t*)alloc((size_t)640 * 1280 * 2);
    float*  vip = (float*)alloc((size_t)8 * 1280 * 4);

    k_cast<<<40960, 256, 0, stream>>>(hs, Xb, (long)32768 * 1280);
    k_cast_pad<<<1280, 256, 0, stream>>>(enc, Eb, 616, 640, 2048);
    k_transpose_cast<<<dim3(40, 40), 256, 0, stream>>>(Wq, WqT, 1280, 1280);
    k_transpose_cast<<<dim3(40, 64), 256, 0, stream>>>(Wk, WkT, 2048, 1280);
    k_transpose_cast<<<dim3(40, 64), 256, 0, stream>>>(Wv, WvT, 2048, 1280);
    k_transpose_cast<<<dim3(40, 40), 256, 0, stream>>>(Wo, WoT, 1280, 1280);
    k_adapter<<<40, 256, 0, stream>>>(ae, Wva, vip);

    // projections — big GEMMs use the XCD swizzle (256 M-tiles, 10 N-tiles, 32 M-tiles/XCD)
    k_gemm_bt<true, false, true><<<2560, 256, 0, stream>>>(Xb, WqT, Qb, nullptr, 32768, 1280, 1280, 10, 32);
    k_gemm_bt<true, false, false><<<dim3(10, 5), 256, 0, stream>>>(Eb, WkT, Kc, nullptr, 640, 1280, 2048, 0, 0);
    k_gemm_bt<true, false, false><<<dim3(10, 5), 256, 0, stream>>>(Eb, WvT, Vc, nullptr, 640, 1280, 2048, 0, 0);

    k_attn<<<dim3(32, 20, 8), 256, 0, stream>>>(Qb, Kc, Vc, vip, Mrg);

    k_gemm_bt<false, true, true><<<2560, 256, 0, stream>>>(Mrg, WoT, out, bo, 32768, 1280, 1280, 10, 32);
}